// Round 5
// baseline (1715.269 us; speedup 1.0000x reference)
//
#include <hip/hip_runtime.h>
#include <math.h>

// ============================================================================
// CapsNet forward, round 5.
//   conv2m v2: wave tile 64x64 (R=6 frag reuse), block 128x128, BK=64,
//   split-K x2 via blockIdx.z with f32 atomicAdd epilogue (k_pinit seeds bias).
//   Numerics identical to round 4 (fp16 hi/lo 3-pass MFMA): absmax must hold.
//   Everything else unchanged from the passing round-4 kernel.
//
// Workspace (bytes):
//   ahi [0, 104857600)            alo [104857600, 209715200)
//   whi [209715200, 220332032)    wlo [220332032, 230948864)
//   caps[230948864, 249823232)    (= p, squashed in place)
//   -- after conv2m, staging region is dead; alias small buffers at 0:
//   spart [0, 2949120)  vsum [2949120, +327680)  vbuf [3276800, +327680)
//   din [3604480, +327680)  h1 [3932160, +1048576)  h2 [4980736, +2097152)
//   total ws use: 249,823,232 bytes (same as round 4, which fit)
// ============================================================================

typedef _Float16 f16x8 __attribute__((ext_vector_type(8)));
typedef float f32x4 __attribute__((ext_vector_type(4)));

// ---------------- conv1: x[512,1,28,28] -> relu -> ahi/alo[b][20][20][256] (x16)
__global__ __launch_bounds__(256) void k_conv1(const float* __restrict__ x,
        const float* __restrict__ w, const float* __restrict__ bias,
        _Float16* __restrict__ ahi, _Float16* __restrict__ alo) {
    __shared__ __align__(16) float xs[784];
    const int b = blockIdx.x;
    const int t = threadIdx.x;                     // = output channel ci
    for (int i = t; i < 784; i += 256) xs[i] = x[b * 784 + i];
    __syncthreads();

    float wr[81];
#pragma unroll
    for (int i = 0; i < 81; ++i) wr[i] = w[t * 81 + i];
    const float bv = bias[t];

    for (int oy = 0; oy < 20; ++oy) {
        float acc[20];
#pragma unroll
        for (int px = 0; px < 20; ++px) acc[px] = bv;
#pragma unroll
        for (int ky = 0; ky < 9; ++ky) {
            const float* xrow = &xs[(oy + ky) * 28];
            float xr[28];
#pragma unroll
            for (int j = 0; j < 7; ++j) {
                float4 v4 = *(const float4*)(xrow + j * 4);
                xr[j * 4 + 0] = v4.x; xr[j * 4 + 1] = v4.y;
                xr[j * 4 + 2] = v4.z; xr[j * 4 + 3] = v4.w;
            }
#pragma unroll
            for (int kx = 0; kx < 9; ++kx) {
                const float wv = wr[ky * 9 + kx];
#pragma unroll
                for (int px = 0; px < 20; ++px)
                    acc[px] = fmaf(wv, xr[px + kx], acc[px]);
            }
        }
#pragma unroll
        for (int px = 0; px < 20; ++px) {
            const float v16 = fmaxf(acc[px], 0.f) * 16.f;
            const _Float16 hi = (_Float16)v16;
            const _Float16 lo = (_Float16)(v16 - (float)hi);
            const int idx = (b * 400 + oy * 20 + px) * 256 + t;
            ahi[idx] = hi;
            alo[idx] = lo;
        }
    }
}

// ---------------- W2 convert: pc_w[n][ci][tap] -> whi/wlo[n][tap*256+ci] (x16)
__global__ __launch_bounds__(256) void k_wcvt(const float* __restrict__ w2,
        _Float16* __restrict__ whi, _Float16* __restrict__ wlo) {
    const int i = blockIdx.x * 256 + threadIdx.x;  // 5,308,416 outputs
    const int n = i / 20736;
    const int r = i - n * 20736;
    const int tap = r >> 8;
    const int ci = r & 255;
    const float v = w2[(n * 256 + ci) * 81 + tap] * 16.f;
    const _Float16 hi = (_Float16)v;
    whi[i] = hi;
    wlo[i] = (_Float16)(v - (float)hi);
}

// ---------------- p init: p[(b*256+n)*36+pix] = bias[n]  (epilogue atomicAdds)
__global__ __launch_bounds__(256) void k_pinit(const float* __restrict__ bias,
        float* __restrict__ p) {
    const int idx = blockIdx.x * 256 + threadIdx.x;   // 4,718,592
    const int q = idx / 36;                            // b*256+n
    p[idx] = bias[q & 255];
}

// ---------------- conv2 MFMA implicit GEMM v2
// C[m,n] += (1/256) sum_{k in kz-half} A[m,k]*W[n,k];  K = 81*256 tap-major.
// Block 128x128, 4 waves (2x2), wave tile 64x64 (4x4 16x16 frags, R=6).
// BK=64; split-K: blockIdx.z=kz handles steps s = 2j+kz (s in [0,324)).
// Staging: global (swizzled source) -> regs -> linear ds_write_b128;
// frag reads use oct' = oct ^ (row&7) (measured 0 bank conflicts in r4).
__global__ __launch_bounds__(256, 2) void k_conv2m(
        const _Float16* __restrict__ ahi, const _Float16* __restrict__ alo,
        const _Float16* __restrict__ whi, const _Float16* __restrict__ wlo,
        float* __restrict__ p) {
    __shared__ __align__(16) _Float16 lds[32768];  // 64 KB
    _Float16* sAhi = lds;                          // [128 rows][64 k]
    _Float16* sAlo = lds + 8192;
    _Float16* sBhi = lds + 16384;                  // [128 rows][64 k]
    _Float16* sBlo = lds + 24576;

    const int t = threadIdx.x;
    const int l = t & 63, w = t >> 6;
    const int m0 = blockIdx.x * 128;
    const int n0 = blockIdx.y * 128;
    const int kz = blockIdx.z;

    // staging: thread t, chunk i covers LDS slot i*256+t -> row i*32+(t>>3),
    // oct' = t&7; swizzled global source oct = (t&7) ^ ((t>>3)&7).
    const int oct = ((t & 7) ^ ((t >> 3) & 7)) * 8;
    int apix[4], wbase[4];
#pragma unroll
    for (int i = 0; i < 4; ++i) {
        const int r = i * 32 + (t >> 3);           // 0..127
        const int m = m0 + r;
        const int b = m / 36, pix = m - b * 36;
        const int oy = pix / 6, ox = pix - oy * 6;
        apix[i] = (b * 400 + oy * 40 + ox * 2) * 256 + oct;
        wbase[i] = (n0 + r) * 20736 + oct;
    }

    f32x4 acc[4][4];
#pragma unroll
    for (int mf = 0; mf < 4; ++mf)
#pragma unroll
        for (int nf = 0; nf < 4; ++nf) acc[mf][nf] = (f32x4){0.f, 0.f, 0.f, 0.f};

    const int wm = (w >> 1) * 64, wn = (w & 1) * 64;
    const int lm = l & 15, lk = l >> 4;

    f16x8 rAh[4], rAl[4], rBh[4], rBl[4];

#define C2_LOAD(s) do { \
        const int tap_ = (s) >> 2; \
        const int ci0_ = ((s) & 3) << 6; \
        const int ky_ = tap_ / 9, kx_ = tap_ - ky_ * 9; \
        const int koff_ = (ky_ * 20 + kx_) * 256 + ci0_; \
        const int k0_ = (s) * 64; \
        _Pragma("unroll") \
        for (int i_ = 0; i_ < 4; ++i_) { \
            rAh[i_] = *(const f16x8*)(ahi + apix[i_] + koff_); \
            rAl[i_] = *(const f16x8*)(alo + apix[i_] + koff_); \
            rBh[i_] = *(const f16x8*)(whi + wbase[i_] + k0_); \
            rBl[i_] = *(const f16x8*)(wlo + wbase[i_] + k0_); \
        } \
    } while (0)

    C2_LOAD(kz);                                   // preload step j=0

    for (int j = 0; j < 162; ++j) {
        __syncthreads();                           // prev readers done with LDS
#pragma unroll
        for (int i = 0; i < 4; ++i) {
            *(f16x8*)(sAhi + i * 2048 + t * 8) = rAh[i];
            *(f16x8*)(sAlo + i * 2048 + t * 8) = rAl[i];
            *(f16x8*)(sBhi + i * 2048 + t * 8) = rBh[i];
            *(f16x8*)(sBlo + i * 2048 + t * 8) = rBl[i];
        }
        __syncthreads();                           // tile visible to all waves
        if (j < 161) C2_LOAD(2 * (j + 1) + kz);    // prefetch hides under MFMA

#pragma unroll
        for (int ks = 0; ks < 2; ++ks) {
            f16x8 afh[4], afl[4];
#pragma unroll
            for (int mf = 0; mf < 4; ++mf) {
                const int row = wm + mf * 16 + lm;
                const int off = row * 64 + ((ks * 4 + lk) ^ (lm & 7)) * 8;
                afh[mf] = *(const f16x8*)&sAhi[off];
                afl[mf] = *(const f16x8*)&sAlo[off];
            }
#pragma unroll
            for (int nf = 0; nf < 4; ++nf) {
                const int row = wn + nf * 16 + lm;
                const int off = row * 64 + ((ks * 4 + lk) ^ (lm & 7)) * 8;
                const f16x8 bh = *(const f16x8*)&sBhi[off];
                const f16x8 bl = *(const f16x8*)&sBlo[off];
#pragma unroll
                for (int mf = 0; mf < 4; ++mf) {
                    acc[mf][nf] = __builtin_amdgcn_mfma_f32_16x16x32_f16(
                        afh[mf], bh, acc[mf][nf], 0, 0, 0);
                    acc[mf][nf] = __builtin_amdgcn_mfma_f32_16x16x32_f16(
                        afh[mf], bl, acc[mf][nf], 0, 0, 0);
                    acc[mf][nf] = __builtin_amdgcn_mfma_f32_16x16x32_f16(
                        afl[mf], bh, acc[mf][nf], 0, 0, 0);
                }
            }
        }
    }
#undef C2_LOAD

    // epilogue: D col(n) = lm, row(m) = lk*4 + r; accumulate split-K partials
#pragma unroll
    for (int nf = 0; nf < 4; ++nf) {
        const int n = n0 + wn + nf * 16 + lm;
#pragma unroll
        for (int mf = 0; mf < 4; ++mf) {
#pragma unroll
            for (int r = 0; r < 4; ++r) {
                const int m = m0 + wm + mf * 16 + lk * 4 + r;
                const int b = m / 36, pix = m - b * 36;
                atomicAdd(&p[(b * 256 + n) * 36 + pix],
                          acc[mf][nf][r] * (1.f / 256.f));
            }
        }
    }
}

// ---------------- squash caps in place: [512*1152][8]
__global__ __launch_bounds__(256) void k_squash(float* __restrict__ pc) {
    const long long i = (long long)blockIdx.x * 256 + threadIdx.x;  // 589824
    float* p = pc + i * 8;
    float4 v0 = *(float4*)p;
    float4 v1 = *(float4*)(p + 4);
    const float sq = v0.x * v0.x + v0.y * v0.y + v0.z * v0.z + v0.w * v0.w
                   + v1.x * v1.x + v1.y * v1.y + v1.z * v1.z + v1.w * v1.w;
    const float sc = (sq / (1.f + sq)) / (sqrtf(sq) + 1e-8f);
    v0.x *= sc; v0.y *= sc; v0.z *= sc; v0.w *= sc;
    v1.x *= sc; v1.y *= sc; v1.z *= sc; v1.w *= sc;
    *(float4*)p = v0;
    *(float4*)(p + 4) = v1;
}

// ---------------- fused routing pass (u_hat recomputed on the fly):
// u[o] = dot8(W[o,n,d,:], caps[b,n,:]);
// c = 0.1 (uniform) or softmax_o( sum_d u[o]*vsum[b,o,d] );
// sp[b,nc,o,d] = sum_{n in chunk} c[o] * u[o]
// grid (512, 9), block 128: thread = (g = t>>4 in [0,8), d = t&15); 16 n each.
__global__ __launch_bounds__(128) void k_route(const float* __restrict__ caps,
        const float* __restrict__ W, const float* __restrict__ vsum,
        float* __restrict__ sp, int uniform) {
    const int b = blockIdx.x, nc = blockIdx.y;
    const int t = threadIdx.x;
    const int d = t & 15, g = t >> 4;
    __shared__ float vs[160];
    __shared__ float red[2][160];
    if (uniform == 0)
        for (int i = t; i < 160; i += 128) vs[i] = vsum[b * 160 + i];
    __syncthreads();

    float sacc[10];
#pragma unroll
    for (int o = 0; o < 10; ++o) sacc[o] = 0.f;

    for (int i = 0; i < 16; ++i) {
        const int n = nc * 128 + i * 8 + g;
        const float* cp = caps + ((long long)b * 1152 + n) * 8;
        const float4 ca = *(const float4*)cp;
        const float4 cb = *(const float4*)(cp + 4);
        float uv[10];
#pragma unroll
        for (int o = 0; o < 10; ++o) {
            const float* wp = W + (((long long)o * 1152 + n) * 16 + d) * 8;
            const float4 wa = *(const float4*)wp;
            const float4 wb = *(const float4*)(wp + 4);
            float s = wa.x * ca.x;
            s = fmaf(wa.y, ca.y, s); s = fmaf(wa.z, ca.z, s); s = fmaf(wa.w, ca.w, s);
            s = fmaf(wb.x, cb.x, s); s = fmaf(wb.y, cb.y, s); s = fmaf(wb.z, cb.z, s);
            s = fmaf(wb.w, cb.w, s);
            uv[o] = s;
        }
        float c[10];
        if (uniform) {
#pragma unroll
            for (int o = 0; o < 10; ++o) c[o] = 0.1f;
        } else {
            float dot[10];
#pragma unroll
            for (int o = 0; o < 10; ++o) {
                float xx = uv[o] * vs[o * 16 + d];
                xx += __shfl_xor(xx, 1);
                xx += __shfl_xor(xx, 2);
                xx += __shfl_xor(xx, 4);
                xx += __shfl_xor(xx, 8);
                dot[o] = xx;
            }
            float mx = dot[0];
#pragma unroll
            for (int o = 1; o < 10; ++o) mx = fmaxf(mx, dot[o]);
            float sum = 0.f;
#pragma unroll
            for (int o = 0; o < 10; ++o) { c[o] = expf(dot[o] - mx); sum += c[o]; }
            const float inv = 1.f / sum;
#pragma unroll
            for (int o = 0; o < 10; ++o) c[o] *= inv;
        }
#pragma unroll
        for (int o = 0; o < 10; ++o) sacc[o] = fmaf(c[o], uv[o], sacc[o]);
    }
    // reduce over g: lane bits 4,5 within wave, then across the 2 waves
#pragma unroll
    for (int o = 0; o < 10; ++o) {
        sacc[o] += __shfl_xor(sacc[o], 16);
        sacc[o] += __shfl_xor(sacc[o], 32);
    }
    const int wv = t >> 6;
    if ((t & 63) < 16) {
#pragma unroll
        for (int o = 0; o < 10; ++o) red[wv][o * 16 + d] = sacc[o];
    }
    __syncthreads();
    for (int i = t; i < 160; i += 128)
        sp[((long long)(b * 9 + nc)) * 160 + i] = red[0][i] + red[1][i];
}

// ---------------- v = squash(sum_ch sp); vsum = first ? v : vsum + v; vbuf = v
__global__ __launch_bounds__(160) void k_squashv(const float* __restrict__ sp,
        float* __restrict__ vsum, float* __restrict__ vbuf, int first) {
    const int b = blockIdx.x, t = threadIdx.x;     // t = o*16+d
    float s = 0.f;
#pragma unroll
    for (int ch = 0; ch < 9; ++ch) s += sp[((long long)(b * 9 + ch)) * 160 + t];
    float sq = s * s;
    sq += __shfl_xor(sq, 1);
    sq += __shfl_xor(sq, 2);
    sq += __shfl_xor(sq, 4);
    sq += __shfl_xor(sq, 8);
    const float sc = (sq / (1.f + sq)) / (sqrtf(sq) + 1e-8f);
    const float v = s * sc;
    vbuf[b * 160 + t] = v;
    vsum[b * 160 + t] = first ? v : (vsum[b * 160 + t] + v);
}

// ---------------- logits = ||v||, dec_in = v * onehot(argmax)
__global__ __launch_bounds__(64) void k_logits(const float* __restrict__ v,
        float* __restrict__ logits, float* __restrict__ dec_in) {
    const int b = blockIdx.x * 64 + threadIdx.x;   // 512
    const float* vp = v + (long long)b * 160;
    float nrm[10];
    int amax = 0;
    float best = -1.f;
#pragma unroll
    for (int o = 0; o < 10; ++o) {
        float s = 0.f;
#pragma unroll
        for (int dd = 0; dd < 16; ++dd) { const float xv = vp[o * 16 + dd]; s = fmaf(xv, xv, s); }
        nrm[o] = sqrtf(s);
        if (nrm[o] > best) { best = nrm[o]; amax = o; }  // first max wins
    }
#pragma unroll
    for (int o = 0; o < 10; ++o) logits[b * 10 + o] = nrm[o];
#pragma unroll
    for (int o = 0; o < 10; ++o)
#pragma unroll
        for (int dd = 0; dd < 16; ++dd)
            dec_in[(long long)b * 160 + o * 16 + dd] = (o == amax) ? vp[o * 16 + dd] : 0.f;
}

// ---------------- dense GEMM: C[M,N] = act(A[M,K] @ W[N,K]^T + bias)
template <int ACT>
__global__ __launch_bounds__(256) void k_gemm(const float* __restrict__ A,
        const float* __restrict__ W, const float* __restrict__ bias,
        float* __restrict__ C, int N, int K) {
    __shared__ float As[16][68];
    __shared__ float Bs[16][68];
    const int m0 = blockIdx.x * 64, n0 = blockIdx.y * 64;
    const int t = threadIdx.x;
    const int kl = t & 15, rr = t >> 4;
    const int tm = t & 15, tn = t >> 4;

    float acc[4][4];
#pragma unroll
    for (int i = 0; i < 4; ++i)
#pragma unroll
        for (int j = 0; j < 4; ++j) acc[i][j] = 0.f;

    for (int k0 = 0; k0 < K; k0 += 16) {
#pragma unroll
        for (int i = 0; i < 4; ++i) {
            As[kl][rr + i * 16] = A[(m0 + rr + i * 16) * K + k0 + kl];
            const int n = n0 + rr + i * 16;
            Bs[kl][rr + i * 16] = (n < N) ? W[(long long)n * K + k0 + kl] : 0.f;
        }
        __syncthreads();
#pragma unroll
        for (int kk = 0; kk < 16; ++kk) {
            float a[4], bb[4];
#pragma unroll
            for (int i = 0; i < 4; ++i) a[i] = As[kk][tm * 4 + i];
#pragma unroll
            for (int j = 0; j < 4; ++j) bb[j] = Bs[kk][tn * 4 + j];
#pragma unroll
            for (int i = 0; i < 4; ++i)
#pragma unroll
                for (int j = 0; j < 4; ++j)
                    acc[i][j] = fmaf(a[i], bb[j], acc[i][j]);
        }
        __syncthreads();
    }
#pragma unroll
    for (int j = 0; j < 4; ++j) {
        const int n = n0 + tn * 4 + j;
        if (n < N) {
            const float bv = bias[n];
#pragma unroll
            for (int i = 0; i < 4; ++i) {
                const int m = m0 + tm * 4 + i;
                float xv = acc[i][j] + bv;
                if (ACT == 0) xv = fmaxf(xv, 0.f);
                else          xv = 1.f / (1.f + expf(-xv));
                C[(long long)m * N + n] = xv;
            }
        }
    }
}

// ============================================================================
extern "C" void kernel_launch(void* const* d_in, const int* in_sizes, int n_in,
                              void* d_out, int out_size, void* d_ws, size_t ws_size,
                              hipStream_t stream) {
    const float* x      = (const float*)d_in[0];
    const float* conv_w = (const float*)d_in[1];
    const float* conv_b = (const float*)d_in[2];
    const float* pc_w   = (const float*)d_in[3];
    const float* pc_b   = (const float*)d_in[4];
    const float* Wrt    = (const float*)d_in[5];
    const float* dw1    = (const float*)d_in[6];
    const float* db1    = (const float*)d_in[7];
    const float* dw2    = (const float*)d_in[8];
    const float* db2    = (const float*)d_in[9];
    const float* dw3    = (const float*)d_in[10];
    const float* db3    = (const float*)d_in[11];

    float* out = (float*)d_out;                 // [0,5120) logits, then recon
    char* wsb  = (char*)d_ws;

    _Float16* ahi = (_Float16*)(wsb);                 // 104,857,600 B
    _Float16* alo = (_Float16*)(wsb + 104857600);
    _Float16* whi = (_Float16*)(wsb + 209715200);     // 10,616,832 B
    _Float16* wlo = (_Float16*)(wsb + 220332032);
    float* caps = (float*)(wsb + 230948864);          // 18,874,368 B
    // staging region dead after conv2m -> alias small buffers at offset 0
    float* spart= (float*)(wsb);                      // 2,949,120 B
    float* vsum = (float*)(wsb + 2949120);
    float* vbuf = (float*)(wsb + 3276800);
    float* din  = (float*)(wsb + 3604480);
    float* h1   = (float*)(wsb + 3932160);
    float* h2   = (float*)(wsb + 4980736);
    // total ws use: 249,823,232 bytes

    k_conv1<<<512, 256, 0, stream>>>(x, conv_w, conv_b, ahi, alo);
    k_wcvt<<<20736, 256, 0, stream>>>(pc_w, whi, wlo);
    k_pinit<<<18432, 256, 0, stream>>>(pc_b, caps);
    k_conv2m<<<dim3(144, 2, 2), 256, 0, stream>>>(ahi, alo, whi, wlo, caps);
    k_squash<<<2304, 256, 0, stream>>>(caps);

    // routing via vsum linearity: b_logit after iter k == u . (v0+..+v_{k-1})
    k_route<<<dim3(512, 9), 128, 0, stream>>>(caps, Wrt, vsum, spart, 1);
    k_squashv<<<512, 160, 0, stream>>>(spart, vsum, vbuf, 1);   // vsum = v0
    k_route<<<dim3(512, 9), 128, 0, stream>>>(caps, Wrt, vsum, spart, 0);
    k_squashv<<<512, 160, 0, stream>>>(spart, vsum, vbuf, 0);   // vsum = v0+v1
    k_route<<<dim3(512, 9), 128, 0, stream>>>(caps, Wrt, vsum, spart, 0);
    k_squashv<<<512, 160, 0, stream>>>(spart, vsum, vbuf, 0);   // vbuf = v2

    k_logits<<<8, 64, 0, stream>>>(vbuf, out, din);

    k_gemm<0><<<dim3(8, 8),  256, 0, stream>>>(din, dw1, db1, h1, 512, 160);
    k_gemm<0><<<dim3(8, 16), 256, 0, stream>>>(h1,  dw2, db2, h2, 1024, 512);
    k_gemm<1><<<dim3(8, 13), 256, 0, stream>>>(h2,  dw3, db3, out + 5120, 784, 1024);
}

// Round 6
// 1708.239 us; speedup vs baseline: 1.0041x; 1.0041x over previous
//
#include <hip/hip_runtime.h>
#include <math.h>

// ============================================================================
// CapsNet forward, round 6.
//   conv2m v3: round-4 geometry (BM=64, BN=128, BK=64, 48 KB LDS, 3 blk/CU)
//     + split-K x4 (k-interleaved, atomicAdd epilogue, k_pinit seeds bias)
//     + depth-2 A prefetch (A is the HBM/L3 stream; B is L3-resident).
//   conv1 split over oy (grid 512x5) for occupancy.
//   Numerics identical to rounds 4/5 (fp16 hi/lo 3-pass MFMA).
//
// Workspace (bytes):
//   ahi [0, 104857600)            alo [104857600, 209715200)
//   whi [209715200, 220332032)    wlo [220332032, 230948864)
//   caps[230948864, 249823232)    (= p, squashed in place)
//   -- after conv2m, staging region is dead; alias small buffers at 0:
//   spart [0, 2949120)  vsum [2949120, +327680)  vbuf [3276800, +327680)
//   din [3604480, +327680)  h1 [3932160, +1048576)  h2 [4980736, +2097152)
//   total ws use: 249,823,232 bytes
// ============================================================================

typedef _Float16 f16x8 __attribute__((ext_vector_type(8)));
typedef float f32x4 __attribute__((ext_vector_type(4)));

// ---------------- conv1: x[512,1,28,28] -> relu -> ahi/alo[b][20][20][256] (x16)
// grid (512, 5): block (b, oy-quad); thread t = output channel.
__global__ __launch_bounds__(256) void k_conv1(const float* __restrict__ x,
        const float* __restrict__ w, const float* __restrict__ bias,
        _Float16* __restrict__ ahi, _Float16* __restrict__ alo) {
    __shared__ __align__(16) float xs[784];
    const int b = blockIdx.x;
    const int oy0 = blockIdx.y * 4;
    const int t = threadIdx.x;                     // = output channel ci
    for (int i = t; i < 784; i += 256) xs[i] = x[b * 784 + i];
    __syncthreads();

    float wr[81];
#pragma unroll
    for (int i = 0; i < 81; ++i) wr[i] = w[t * 81 + i];
    const float bv = bias[t];

    for (int oy = oy0; oy < oy0 + 4; ++oy) {
        float acc[20];
#pragma unroll
        for (int px = 0; px < 20; ++px) acc[px] = bv;
#pragma unroll
        for (int ky = 0; ky < 9; ++ky) {
            const float* xrow = &xs[(oy + ky) * 28];
            float xr[28];
#pragma unroll
            for (int j = 0; j < 7; ++j) {
                float4 v4 = *(const float4*)(xrow + j * 4);
                xr[j * 4 + 0] = v4.x; xr[j * 4 + 1] = v4.y;
                xr[j * 4 + 2] = v4.z; xr[j * 4 + 3] = v4.w;
            }
#pragma unroll
            for (int kx = 0; kx < 9; ++kx) {
                const float wv = wr[ky * 9 + kx];
#pragma unroll
                for (int px = 0; px < 20; ++px)
                    acc[px] = fmaf(wv, xr[px + kx], acc[px]);
            }
        }
#pragma unroll
        for (int px = 0; px < 20; ++px) {
            const float v16 = fmaxf(acc[px], 0.f) * 16.f;
            const _Float16 hi = (_Float16)v16;
            const _Float16 lo = (_Float16)(v16 - (float)hi);
            const int idx = (b * 400 + oy * 20 + px) * 256 + t;
            ahi[idx] = hi;
            alo[idx] = lo;
        }
    }
}

// ---------------- W2 convert: pc_w[n][ci][tap] -> whi/wlo[n][tap*256+ci] (x16)
__global__ __launch_bounds__(256) void k_wcvt(const float* __restrict__ w2,
        _Float16* __restrict__ whi, _Float16* __restrict__ wlo) {
    const int i = blockIdx.x * 256 + threadIdx.x;  // 5,308,416 outputs
    const int n = i / 20736;
    const int r = i - n * 20736;
    const int tap = r >> 8;
    const int ci = r & 255;
    const float v = w2[(n * 256 + ci) * 81 + tap] * 16.f;
    const _Float16 hi = (_Float16)v;
    whi[i] = hi;
    wlo[i] = (_Float16)(v - (float)hi);
}

// ---------------- p init: p[(b*256+n)*36+pix] = bias[n]  (epilogue atomicAdds)
__global__ __launch_bounds__(256) void k_pinit(const float* __restrict__ bias,
        float* __restrict__ p) {
    const int idx = blockIdx.x * 256 + threadIdx.x;   // 4,718,592
    const int q = idx / 36;                            // b*256+n
    p[idx] = bias[q & 255];
}

// ---------------- conv2 MFMA implicit GEMM v3
// C[m,n] += (1/256) sum_{k in kz slice} A[m,k]*W[n,k]; K = 81*256 tap-major.
// Tile BM=64 BN=128 BK=64, 4 waves (2x2), wave tile 32x64. Split-K x4:
// blockIdx.z = kz, steps s = 4j + kz, j in [0,81).
// Staging: global (swizzled source) -> regs -> linear ds_write_b128; frag
// reads oct' = oct ^ (row&7) (0 bank conflicts measured r4/r5).
// A staged depth-2 (sets 0/1, parity-unrolled); B depth-1 (L3-resident).
__global__ __launch_bounds__(256, 3) void k_conv2m(
        const _Float16* __restrict__ ahi, const _Float16* __restrict__ alo,
        const _Float16* __restrict__ whi, const _Float16* __restrict__ wlo,
        float* __restrict__ p) {
    __shared__ __align__(16) _Float16 lds[24576];  // 48 KB
    _Float16* sAhi = lds;                          // [64 rows][64 k]
    _Float16* sAlo = lds + 4096;
    _Float16* sBhi = lds + 8192;                   // [128 rows][64 k]
    _Float16* sBlo = lds + 16384;

    const int t = threadIdx.x;
    const int l = t & 63, w = t >> 6;
    const int m0 = blockIdx.x * 64;
    const int n0 = blockIdx.y * 128;
    const int kz = blockIdx.z;

    // staging: issue block (i*4+w) covers rows (i*4+w)*8 + (l>>3);
    // lane writes LDS linearly at slot l*8; source col = ((l&7)^(l>>3))*8.
    const int sr = l >> 3;                         // 0..7
    const int oct = ((l & 7) ^ sr) * 8;            // swizzled source ci-offset
    int apix[2];
#pragma unroll
    for (int i = 0; i < 2; ++i) {
        const int r = w * 8 + sr + i * 32;         // A row 0..63
        const int m = m0 + r;
        const int b = m / 36, pix = m - b * 36;
        const int oy = pix / 6, ox = pix - oy * 6;
        apix[i] = (b * 400 + oy * 40 + ox * 2) * 256 + oct;
    }
    int wbase[4];
#pragma unroll
    for (int i = 0; i < 4; ++i) {
        const int nr = (i * 4 + w) * 8 + sr;       // B row 0..127
        wbase[i] = (n0 + nr) * 20736 + oct;
    }

    f32x4 acc[2][4];
#pragma unroll
    for (int mf = 0; mf < 2; ++mf)
#pragma unroll
        for (int nf = 0; nf < 4; ++nf) acc[mf][nf] = (f32x4){0.f, 0.f, 0.f, 0.f};

    const int wm = (w >> 1) * 32, wn = (w & 1) * 64;
    const int lm = l & 15, lk = l >> 4;

    f16x8 rAh0[2], rAl0[2], rAh1[2], rAl1[2], rBh[4], rBl[4];

    // k = s*64 (tap-major layout makes k linear in s); pixel offset per tap.
#define KOFF(s_) (((((s_) >> 2) / 9) * 20 + (((s_) >> 2) % 9)) * 256 + (((s_) & 3) << 6))

#define LOADA(S, s_) do { \
        const int koff_ = KOFF(s_); \
        rAh##S[0] = *(const f16x8*)(ahi + apix[0] + koff_); \
        rAl##S[0] = *(const f16x8*)(alo + apix[0] + koff_); \
        rAh##S[1] = *(const f16x8*)(ahi + apix[1] + koff_); \
        rAl##S[1] = *(const f16x8*)(alo + apix[1] + koff_); \
    } while (0)

#define LOADB(s_) do { \
        const int k0_ = (s_) * 64; \
        _Pragma("unroll") \
        for (int i_ = 0; i_ < 4; ++i_) { \
            rBh[i_] = *(const f16x8*)(whi + wbase[i_] + k0_); \
            rBl[i_] = *(const f16x8*)(wlo + wbase[i_] + k0_); \
        } \
    } while (0)

#define MFMA_PHASE() do { \
        _Pragma("unroll") \
        for (int ks = 0; ks < 2; ++ks) { \
            f16x8 afh[2], afl[2]; \
            _Pragma("unroll") \
            for (int mf = 0; mf < 2; ++mf) { \
                const int row = wm + mf * 16 + lm; \
                const int off = row * 64 + ((ks * 4 + lk) ^ (lm & 7)) * 8; \
                afh[mf] = *(const f16x8*)&sAhi[off]; \
                afl[mf] = *(const f16x8*)&sAlo[off]; \
            } \
            _Pragma("unroll") \
            for (int nf = 0; nf < 4; ++nf) { \
                const int row = wn + nf * 16 + lm; \
                const int off = row * 64 + ((ks * 4 + lk) ^ (lm & 7)) * 8; \
                const f16x8 bh = *(const f16x8*)&sBhi[off]; \
                const f16x8 bl = *(const f16x8*)&sBlo[off]; \
                _Pragma("unroll") \
                for (int mf = 0; mf < 2; ++mf) { \
                    acc[mf][nf] = __builtin_amdgcn_mfma_f32_16x16x32_f16( \
                        afh[mf], bh, acc[mf][nf], 0, 0, 0); \
                    acc[mf][nf] = __builtin_amdgcn_mfma_f32_16x16x32_f16( \
                        afh[mf], bl, acc[mf][nf], 0, 0, 0); \
                    acc[mf][nf] = __builtin_amdgcn_mfma_f32_16x16x32_f16( \
                        afl[mf], bh, acc[mf][nf], 0, 0, 0); \
                } \
            } \
        } \
    } while (0)

    // BODY(j, S): write tile j (A set S + B), then prefetch A for j+2 into S
    // (2-step latency cover) and B for j+1 (1-step), then MFMA on tile j.
#define BODY(jv, S) do { \
        __syncthreads(); \
        *(f16x8*)(sAhi + (0 * 4 + w) * 512 + l * 8) = rAh##S[0]; \
        *(f16x8*)(sAlo + (0 * 4 + w) * 512 + l * 8) = rAl##S[0]; \
        *(f16x8*)(sAhi + (1 * 4 + w) * 512 + l * 8) = rAh##S[1]; \
        *(f16x8*)(sAlo + (1 * 4 + w) * 512 + l * 8) = rAl##S[1]; \
        _Pragma("unroll") \
        for (int i_ = 0; i_ < 4; ++i_) { \
            *(f16x8*)(sBhi + (i_ * 4 + w) * 512 + l * 8) = rBh[i_]; \
            *(f16x8*)(sBlo + (i_ * 4 + w) * 512 + l * 8) = rBl[i_]; \
        } \
        __syncthreads(); \
        if ((jv) + 2 <= 80) LOADA(S, 4 * ((jv) + 2) + kz); \
        if ((jv) + 1 <= 80) LOADB(4 * ((jv) + 1) + kz); \
        MFMA_PHASE(); \
    } while (0)

    LOADA(0, kz);            // j=0
    LOADA(1, 4 + kz);        // j=1
    LOADB(kz);               // j=0

    for (int jj = 0; jj < 41; ++jj) {
        BODY(2 * jj, 0);
        if (jj < 40) BODY(2 * jj + 1, 1);
    }
#undef BODY
#undef MFMA_PHASE
#undef LOADB
#undef LOADA
#undef KOFF

    // epilogue: D col(n) = lm, row(m) = lk*4 + r; split-K partial accumulate
#pragma unroll
    for (int nf = 0; nf < 4; ++nf) {
        const int n = n0 + wn + nf * 16 + lm;
#pragma unroll
        for (int mf = 0; mf < 2; ++mf) {
#pragma unroll
            for (int r = 0; r < 4; ++r) {
                const int m = m0 + wm + mf * 16 + lk * 4 + r;
                const int b = m / 36, pix = m - b * 36;
                atomicAdd(&p[(b * 256 + n) * 36 + pix],
                          acc[mf][nf][r] * (1.f / 256.f));
            }
        }
    }
}

// ---------------- squash caps in place: [512*1152][8]
__global__ __launch_bounds__(256) void k_squash(float* __restrict__ pc) {
    const long long i = (long long)blockIdx.x * 256 + threadIdx.x;  // 589824
    float* p = pc + i * 8;
    float4 v0 = *(float4*)p;
    float4 v1 = *(float4*)(p + 4);
    const float sq = v0.x * v0.x + v0.y * v0.y + v0.z * v0.z + v0.w * v0.w
                   + v1.x * v1.x + v1.y * v1.y + v1.z * v1.z + v1.w * v1.w;
    const float sc = (sq / (1.f + sq)) / (sqrtf(sq) + 1e-8f);
    v0.x *= sc; v0.y *= sc; v0.z *= sc; v0.w *= sc;
    v1.x *= sc; v1.y *= sc; v1.z *= sc; v1.w *= sc;
    *(float4*)p = v0;
    *(float4*)(p + 4) = v1;
}

// ---------------- fused routing pass (u_hat recomputed on the fly):
// u[o] = dot8(W[o,n,d,:], caps[b,n,:]);
// c = 0.1 (uniform) or softmax_o( sum_d u[o]*vsum[b,o,d] );
// sp[b,nc,o,d] = sum_{n in chunk} c[o] * u[o]
// grid (512, 9), block 128: thread = (g = t>>4 in [0,8), d = t&15); 16 n each.
__global__ __launch_bounds__(128) void k_route(const float* __restrict__ caps,
        const float* __restrict__ W, const float* __restrict__ vsum,
        float* __restrict__ sp, int uniform) {
    const int b = blockIdx.x, nc = blockIdx.y;
    const int t = threadIdx.x;
    const int d = t & 15, g = t >> 4;
    __shared__ float vs[160];
    __shared__ float red[2][160];
    if (uniform == 0)
        for (int i = t; i < 160; i += 128) vs[i] = vsum[b * 160 + i];
    __syncthreads();

    float sacc[10];
#pragma unroll
    for (int o = 0; o < 10; ++o) sacc[o] = 0.f;

    for (int i = 0; i < 16; ++i) {
        const int n = nc * 128 + i * 8 + g;
        const float* cp = caps + ((long long)b * 1152 + n) * 8;
        const float4 ca = *(const float4*)cp;
        const float4 cb = *(const float4*)(cp + 4);
        float uv[10];
#pragma unroll
        for (int o = 0; o < 10; ++o) {
            const float* wp = W + (((long long)o * 1152 + n) * 16 + d) * 8;
            const float4 wa = *(const float4*)wp;
            const float4 wb = *(const float4*)(wp + 4);
            float s = wa.x * ca.x;
            s = fmaf(wa.y, ca.y, s); s = fmaf(wa.z, ca.z, s); s = fmaf(wa.w, ca.w, s);
            s = fmaf(wb.x, cb.x, s); s = fmaf(wb.y, cb.y, s); s = fmaf(wb.z, cb.z, s);
            s = fmaf(wb.w, cb.w, s);
            uv[o] = s;
        }
        float c[10];
        if (uniform) {
#pragma unroll
            for (int o = 0; o < 10; ++o) c[o] = 0.1f;
        } else {
            float dot[10];
#pragma unroll
            for (int o = 0; o < 10; ++o) {
                float xx = uv[o] * vs[o * 16 + d];
                xx += __shfl_xor(xx, 1);
                xx += __shfl_xor(xx, 2);
                xx += __shfl_xor(xx, 4);
                xx += __shfl_xor(xx, 8);
                dot[o] = xx;
            }
            float mx = dot[0];
#pragma unroll
            for (int o = 1; o < 10; ++o) mx = fmaxf(mx, dot[o]);
            float sum = 0.f;
#pragma unroll
            for (int o = 0; o < 10; ++o) { c[o] = expf(dot[o] - mx); sum += c[o]; }
            const float inv = 1.f / sum;
#pragma unroll
            for (int o = 0; o < 10; ++o) c[o] *= inv;
        }
#pragma unroll
        for (int o = 0; o < 10; ++o) sacc[o] = fmaf(c[o], uv[o], sacc[o]);
    }
    // reduce over g: lane bits 4,5 within wave, then across the 2 waves
#pragma unroll
    for (int o = 0; o < 10; ++o) {
        sacc[o] += __shfl_xor(sacc[o], 16);
        sacc[o] += __shfl_xor(sacc[o], 32);
    }
    const int wv = t >> 6;
    if ((t & 63) < 16) {
#pragma unroll
        for (int o = 0; o < 10; ++o) red[wv][o * 16 + d] = sacc[o];
    }
    __syncthreads();
    for (int i = t; i < 160; i += 128)
        sp[((long long)(b * 9 + nc)) * 160 + i] = red[0][i] + red[1][i];
}

// ---------------- v = squash(sum_ch sp); vsum = first ? v : vsum + v; vbuf = v
__global__ __launch_bounds__(160) void k_squashv(const float* __restrict__ sp,
        float* __restrict__ vsum, float* __restrict__ vbuf, int first) {
    const int b = blockIdx.x, t = threadIdx.x;     // t = o*16+d
    float s = 0.f;
#pragma unroll
    for (int ch = 0; ch < 9; ++ch) s += sp[((long long)(b * 9 + ch)) * 160 + t];
    float sq = s * s;
    sq += __shfl_xor(sq, 1);
    sq += __shfl_xor(sq, 2);
    sq += __shfl_xor(sq, 4);
    sq += __shfl_xor(sq, 8);
    const float sc = (sq / (1.f + sq)) / (sqrtf(sq) + 1e-8f);
    const float v = s * sc;
    vbuf[b * 160 + t] = v;
    vsum[b * 160 + t] = first ? v : (vsum[b * 160 + t] + v);
}

// ---------------- logits = ||v||, dec_in = v * onehot(argmax)
__global__ __launch_bounds__(64) void k_logits(const float* __restrict__ v,
        float* __restrict__ logits, float* __restrict__ dec_in) {
    const int b = blockIdx.x * 64 + threadIdx.x;   // 512
    const float* vp = v + (long long)b * 160;
    float nrm[10];
    int amax = 0;
    float best = -1.f;
#pragma unroll
    for (int o = 0; o < 10; ++o) {
        float s = 0.f;
#pragma unroll
        for (int dd = 0; dd < 16; ++dd) { const float xv = vp[o * 16 + dd]; s = fmaf(xv, xv, s); }
        nrm[o] = sqrtf(s);
        if (nrm[o] > best) { best = nrm[o]; amax = o; }  // first max wins
    }
#pragma unroll
    for (int o = 0; o < 10; ++o) logits[b * 10 + o] = nrm[o];
#pragma unroll
    for (int o = 0; o < 10; ++o)
#pragma unroll
        for (int dd = 0; dd < 16; ++dd)
            dec_in[(long long)b * 160 + o * 16 + dd] = (o == amax) ? vp[o * 16 + dd] : 0.f;
}

// ---------------- dense GEMM: C[M,N] = act(A[M,K] @ W[N,K]^T + bias)
template <int ACT>
__global__ __launch_bounds__(256) void k_gemm(const float* __restrict__ A,
        const float* __restrict__ W, const float* __restrict__ bias,
        float* __restrict__ C, int N, int K) {
    __shared__ float As[16][68];
    __shared__ float Bs[16][68];
    const int m0 = blockIdx.x * 64, n0 = blockIdx.y * 64;
    const int t = threadIdx.x;
    const int kl = t & 15, rr = t >> 4;
    const int tm = t & 15, tn = t >> 4;

    float acc[4][4];
#pragma unroll
    for (int i = 0; i < 4; ++i)
#pragma unroll
        for (int j = 0; j < 4; ++j) acc[i][j] = 0.f;

    for (int k0 = 0; k0 < K; k0 += 16) {
#pragma unroll
        for (int i = 0; i < 4; ++i) {
            As[kl][rr + i * 16] = A[(m0 + rr + i * 16) * K + k0 + kl];
            const int n = n0 + rr + i * 16;
            Bs[kl][rr + i * 16] = (n < N) ? W[(long long)n * K + k0 + kl] : 0.f;
        }
        __syncthreads();
#pragma unroll
        for (int kk = 0; kk < 16; ++kk) {
            float a[4], bb[4];
#pragma unroll
            for (int i = 0; i < 4; ++i) a[i] = As[kk][tm * 4 + i];
#pragma unroll
            for (int j = 0; j < 4; ++j) bb[j] = Bs[kk][tn * 4 + j];
#pragma unroll
            for (int i = 0; i < 4; ++i)
#pragma unroll
                for (int j = 0; j < 4; ++j)
                    acc[i][j] = fmaf(a[i], bb[j], acc[i][j]);
        }
        __syncthreads();
    }
#pragma unroll
    for (int j = 0; j < 4; ++j) {
        const int n = n0 + tn * 4 + j;
        if (n < N) {
            const float bv = bias[n];
#pragma unroll
            for (int i = 0; i < 4; ++i) {
                const int m = m0 + tm * 4 + i;
                float xv = acc[i][j] + bv;
                if (ACT == 0) xv = fmaxf(xv, 0.f);
                else          xv = 1.f / (1.f + expf(-xv));
                C[(long long)m * N + n] = xv;
            }
        }
    }
}

// ============================================================================
extern "C" void kernel_launch(void* const* d_in, const int* in_sizes, int n_in,
                              void* d_out, int out_size, void* d_ws, size_t ws_size,
                              hipStream_t stream) {
    const float* x      = (const float*)d_in[0];
    const float* conv_w = (const float*)d_in[1];
    const float* conv_b = (const float*)d_in[2];
    const float* pc_w   = (const float*)d_in[3];
    const float* pc_b   = (const float*)d_in[4];
    const float* Wrt    = (const float*)d_in[5];
    const float* dw1    = (const float*)d_in[6];
    const float* db1    = (const float*)d_in[7];
    const float* dw2    = (const float*)d_in[8];
    const float* db2    = (const float*)d_in[9];
    const float* dw3    = (const float*)d_in[10];
    const float* db3    = (const float*)d_in[11];

    float* out = (float*)d_out;                 // [0,5120) logits, then recon
    char* wsb  = (char*)d_ws;

    _Float16* ahi = (_Float16*)(wsb);                 // 104,857,600 B
    _Float16* alo = (_Float16*)(wsb + 104857600);
    _Float16* whi = (_Float16*)(wsb + 209715200);     // 10,616,832 B
    _Float16* wlo = (_Float16*)(wsb + 220332032);
    float* caps = (float*)(wsb + 230948864);          // 18,874,368 B
    // staging region dead after conv2m -> alias small buffers at offset 0
    float* spart= (float*)(wsb);                      // 2,949,120 B
    float* vsum = (float*)(wsb + 2949120);
    float* vbuf = (float*)(wsb + 3276800);
    float* din  = (float*)(wsb + 3604480);
    float* h1   = (float*)(wsb + 3932160);
    float* h2   = (float*)(wsb + 4980736);
    // total ws use: 249,823,232 bytes

    k_conv1<<<dim3(512, 5), 256, 0, stream>>>(x, conv_w, conv_b, ahi, alo);
    k_wcvt<<<20736, 256, 0, stream>>>(pc_w, whi, wlo);
    k_pinit<<<18432, 256, 0, stream>>>(pc_b, caps);
    k_conv2m<<<dim3(288, 2, 4), 256, 0, stream>>>(ahi, alo, whi, wlo, caps);
    k_squash<<<2304, 256, 0, stream>>>(caps);

    // routing via vsum linearity: b_logit after iter k == u . (v0+..+v_{k-1})
    k_route<<<dim3(512, 9), 128, 0, stream>>>(caps, Wrt, vsum, spart, 1);
    k_squashv<<<512, 160, 0, stream>>>(spart, vsum, vbuf, 1);   // vsum = v0
    k_route<<<dim3(512, 9), 128, 0, stream>>>(caps, Wrt, vsum, spart, 0);
    k_squashv<<<512, 160, 0, stream>>>(spart, vsum, vbuf, 0);   // vsum = v0+v1
    k_route<<<dim3(512, 9), 128, 0, stream>>>(caps, Wrt, vsum, spart, 0);
    k_squashv<<<512, 160, 0, stream>>>(spart, vsum, vbuf, 0);   // vbuf = v2

    k_logits<<<8, 64, 0, stream>>>(vbuf, out, din);

    k_gemm<0><<<dim3(8, 8),  256, 0, stream>>>(din, dw1, db1, h1, 512, 160);
    k_gemm<0><<<dim3(8, 16), 256, 0, stream>>>(h1,  dw2, db2, h2, 1024, 512);
    k_gemm<1><<<dim3(8, 13), 256, 0, stream>>>(h2,  dw3, db3, out + 5120, 784, 1024);
}